// Round 1
// baseline (4199.880 us; speedup 1.0000x reference)
//
#include <hip/hip_runtime.h>
#include <cmath>

// ---- problem constants ----
constexpr int DM     = 768;     // d_model
constexpr int DI     = 1536;    // d_inner
constexpr int DI2    = 3072;    // 2*d_inner
constexpr int DSTATE = 16;
constexpr int DTRANK = 48;
constexpr int NDBC   = 80;      // dt_rank + 2*d_state
constexpr int BB     = 2;
constexpr int LL     = 1024;
constexpr int NT     = BB * LL; // 2048 tokens
constexpr int NVOCAB = 32000;
constexpr float EPSF = 1e-5f;

// ------------------- embedding gather -------------------
__global__ void embed_kernel(const int* __restrict__ x, const float* __restrict__ W,
                             float* __restrict__ h) {
    int t = blockIdx.x;
    int row = x[t];
    const float4* src = (const float4*)(W + (size_t)row * DM);
    float4* dst = (float4*)(h + (size_t)t * DM);
    for (int i = threadIdx.x; i < DM / 4; i += blockDim.x) dst[i] = src[i];
}

// ------------------- per-token RMSNorm -------------------
__global__ __launch_bounds__(256) void rmsnorm_kernel(const float* __restrict__ x,
                                                      const float* __restrict__ w,
                                                      float* __restrict__ o) {
    int t = blockIdx.x;
    const float* xr = x + (size_t)t * DM;
    float s = 0.f;
    for (int i = threadIdx.x; i < DM; i += 256) { float v = xr[i]; s += v * v; }
    #pragma unroll
    for (int off = 32; off >= 1; off >>= 1) s += __shfl_down(s, off, 64);
    __shared__ float wsum[4];
    if ((threadIdx.x & 63) == 0) wsum[threadIdx.x >> 6] = s;
    __syncthreads();
    float tot = wsum[0] + wsum[1] + wsum[2] + wsum[3];
    float r = rsqrtf(tot / DM + EPSF);
    float* orow = o + (size_t)t * DM;
    for (int i = threadIdx.x; i < DM; i += 256) orow[i] = xr[i] * r * w[i];
}

// ------------------- tiled fp32 GEMM, C[m,n] = sum_k A[m,k]*W[n,k] -------------------
// A: M x K (row stride lda), W: N x K (row stride ldw), C: M x ldc
// optional bias[n], optional residual add (resid[m*ldc+n]), act: 0=none, 1=softplus
// Requires: M % 64 == 0, K % 16 == 0. N arbitrary (guarded).
constexpr int BM = 64, BN = 64, BK = 16;
__global__ __launch_bounds__(256) void sgemm_bt(const float* __restrict__ A, int lda,
                                                const float* __restrict__ W, int ldw,
                                                float* __restrict__ C, int ldc,
                                                int M, int N, int K,
                                                const float* __restrict__ bias,
                                                const float* __restrict__ resid,
                                                int act) {
    __shared__ float As[BK][BM];
    __shared__ float Ws[BK][BN];
    const int m0 = blockIdx.x * BM;   // x = M tiles (consecutive blocks share W tile via L2)
    const int n0 = blockIdx.y * BN;
    const int tid = threadIdx.x;
    const int tn = tid & 15, tm = tid >> 4;
    const int lr = tid >> 2;          // 0..63: tile row for loads
    const int lk = (tid & 3) * 4;     // k offset for float4 loads

    float acc[4][4] = {};

    for (int k0 = 0; k0 < K; k0 += BK) {
        // A tile: 64 rows x 16 k, one float4 per thread
        {
            float4 v = *(const float4*)(A + (size_t)(m0 + lr) * lda + k0 + lk);
            As[lk + 0][lr] = v.x; As[lk + 1][lr] = v.y;
            As[lk + 2][lr] = v.z; As[lk + 3][lr] = v.w;
            int n = n0 + lr;
            float4 u = make_float4(0.f, 0.f, 0.f, 0.f);
            if (n < N) u = *(const float4*)(W + (size_t)n * ldw + k0 + lk);
            Ws[lk + 0][lr] = u.x; Ws[lk + 1][lr] = u.y;
            Ws[lk + 2][lr] = u.z; Ws[lk + 3][lr] = u.w;
        }
        __syncthreads();
        #pragma unroll
        for (int kk = 0; kk < BK; ++kk) {
            float4 a = *(const float4*)&As[kk][tm * 4];
            float4 w = *(const float4*)&Ws[kk][tn * 4];
            acc[0][0] += a.x * w.x; acc[0][1] += a.x * w.y; acc[0][2] += a.x * w.z; acc[0][3] += a.x * w.w;
            acc[1][0] += a.y * w.x; acc[1][1] += a.y * w.y; acc[1][2] += a.y * w.z; acc[1][3] += a.y * w.w;
            acc[2][0] += a.z * w.x; acc[2][1] += a.z * w.y; acc[2][2] += a.z * w.z; acc[2][3] += a.z * w.w;
            acc[3][0] += a.w * w.x; acc[3][1] += a.w * w.y; acc[3][2] += a.w * w.z; acc[3][3] += a.w * w.w;
        }
        __syncthreads();
    }

    #pragma unroll
    for (int i = 0; i < 4; ++i) {
        int m = m0 + tm * 4 + i;
        #pragma unroll
        for (int j = 0; j < 4; ++j) {
            int n = n0 + tn * 4 + j;
            if (n < N) {
                float v = acc[i][j];
                if (bias)  v += bias[n];
                if (resid) v += resid[(size_t)m * ldc + n];
                if (act == 1) v = (v > 20.f) ? v : log1pf(expf(v));
                C[(size_t)m * ldc + n] = v;
            }
        }
    }
}

// ------------------- causal depthwise conv (k=4) + bias + silu -------------------
// input: xz (NT x 3072), xa part = cols [0,1536); output xa_silu (NT x 1536)
__global__ void conv_silu_kernel(const float* __restrict__ xz, const float* __restrict__ cw,
                                 const float* __restrict__ cb, float* __restrict__ xa) {
    int idx = blockIdx.x * blockDim.x + threadIdx.x;
    if (idx >= NT * DI) return;
    int e = idx % DI;
    int t = idx / DI;
    int l = t & (LL - 1);
    float acc = cb[e];
    #pragma unroll
    for (int k = 0; k < 4; ++k) {
        int ll = l - 3 + k;
        if (ll >= 0) acc += cw[e * 4 + k] * xz[(size_t)(t - 3 + k) * DI2 + e];
    }
    xa[idx] = acc / (1.f + expf(-acc));   // silu
}

// ------------------- fused selective scan -------------------
// thread = (b, e, n): n = tid&15. Sequential over L. deltaA/deltaBx on the fly.
// emits ys[t,e] = (sum_n h*C + D[e]*xa) * silu(z)
__global__ __launch_bounds__(256) void scan_kernel(const float* __restrict__ delta,  // NT x DI
                                                   const float* __restrict__ xa,     // NT x DI
                                                   const float* __restrict__ dbc,    // NT x 80
                                                   const float* __restrict__ xz,     // NT x 3072 (z at +DI)
                                                   const float* __restrict__ A_log,  // DI x 16
                                                   const float* __restrict__ Dp,     // DI
                                                   float* __restrict__ ys) {         // NT x DI
    const int n = threadIdx.x & 15;
    const int e = blockIdx.x * 16 + (threadIdx.x >> 4);
    const int b = blockIdx.y;
    const float Aen = -expf(A_log[e * 16 + n]);
    const float dpe = Dp[e];
    float h = 0.f;
    const int base = b * LL;
    for (int l = 0; l < LL; ++l) {
        const int t = base + l;
        float d  = delta[(size_t)t * DI + e];
        float xv = xa[(size_t)t * DI + e];
        float bm = dbc[(size_t)t * NDBC + DTRANK + n];
        float cm = dbc[(size_t)t * NDBC + DTRANK + DSTATE + n];
        float dA = expf(d * Aen);
        h = dA * h + d * bm * xv;
        float y = h * cm;
        y += __shfl_xor(y, 8, 64);
        y += __shfl_xor(y, 4, 64);
        y += __shfl_xor(y, 2, 64);
        y += __shfl_xor(y, 1, 64);
        if (n == 0) {
            float z = xz[(size_t)t * DI2 + DI + e];
            float sz = z / (1.f + expf(-z));
            ys[(size_t)t * DI + e] = (y + dpe * xv) * sz;
        }
    }
}

// ------------------- host launcher -------------------
extern "C" void kernel_launch(void* const* d_in, const int* in_sizes, int n_in,
                              void* d_out, int out_size, void* d_ws, size_t ws_size,
                              hipStream_t stream) {
    const int*   x        = (const int*)  d_in[0];
    const float* embed_W  = (const float*)d_in[1];
    const float* norm_w   = (const float*)d_in[2];   // (2, 768)
    const float* in_w     = (const float*)d_in[3];   // (2, 3072, 768)
    const float* conv_w   = (const float*)d_in[4];   // (2, 1536, 4)
    const float* conv_b   = (const float*)d_in[5];   // (2, 1536)
    const float* xproj_w  = (const float*)d_in[6];   // (2, 80, 1536)
    const float* dt_w     = (const float*)d_in[7];   // (2, 1536, 48)
    const float* dt_b     = (const float*)d_in[8];   // (2, 1536)
    const float* A_log    = (const float*)d_in[9];   // (2, 1536, 16)
    const float* D_param  = (const float*)d_in[10];  // (2, 1536)
    const float* out_w    = (const float*)d_in[11];  // (2, 768, 1536)
    const float* normf_w  = (const float*)d_in[12];  // (768,)
    const float* head_w   = (const float*)d_in[13];  // (32000, 768)
    const float* head_b   = (const float*)d_in[14];  // (32000,)
    float* logits = (float*)d_out;

    // workspace carve-up (floats)
    float* ws = (float*)d_ws;
    float* h     = ws;                    // NT*DM      = 1,572,864
    float* xn    = h     + (size_t)NT * DM;
    float* xz    = xn    + (size_t)NT * DM;      // NT*3072
    float* xa    = xz    + (size_t)NT * DI2;     // NT*1536
    float* dbc   = xa    + (size_t)NT * DI;      // NT*80
    float* delta = dbc   + (size_t)NT * NDBC;    // NT*1536
    float* ysb   = delta + (size_t)NT * DI;      // NT*1536

    // 1. embedding
    embed_kernel<<<NT, 192, 0, stream>>>(x, embed_W, h);

    for (int i = 0; i < 2; ++i) {
        // 2. rmsnorm
        rmsnorm_kernel<<<NT, 256, 0, stream>>>(h, norm_w + (size_t)i * DM, xn);
        // 3. in_proj: xz = xn @ in_w^T   (2048 x 3072, K=768)
        sgemm_bt<<<dim3(NT / BM, DI2 / BN), 256, 0, stream>>>(
            xn, DM, in_w + (size_t)i * DI2 * DM, DM, xz, DI2,
            NT, DI2, DM, nullptr, nullptr, 0);
        // 4. conv + silu
        conv_silu_kernel<<<(NT * DI + 255) / 256, 256, 0, stream>>>(
            xz, conv_w + (size_t)i * DI * 4, conv_b + (size_t)i * DI, xa);
        // 5. x_proj: dbc = xa @ xproj_w^T  (2048 x 80, K=1536)
        sgemm_bt<<<dim3(NT / BM, (NDBC + BN - 1) / BN), 256, 0, stream>>>(
            xa, DI, xproj_w + (size_t)i * NDBC * DI, DI, dbc, NDBC,
            NT, NDBC, DI, nullptr, nullptr, 0);
        // 6. dt_proj + bias + softplus: delta (2048 x 1536, K=48), A = dbc[:, :48]
        sgemm_bt<<<dim3(NT / BM, DI / BN), 256, 0, stream>>>(
            dbc, NDBC, dt_w + (size_t)i * DI * DTRANK, DTRANK, delta, DI,
            NT, DI, DTRANK, dt_b + (size_t)i * DI, nullptr, 1);
        // 7. fused selective scan -> ys
        scan_kernel<<<dim3(DI / 16, BB), 256, 0, stream>>>(
            delta, xa, dbc, xz, A_log + (size_t)i * DI * DSTATE,
            D_param + (size_t)i * DI, ysb);
        // 8. out_proj + residual: h = h + ys @ out_w^T  (2048 x 768, K=1536)
        sgemm_bt<<<dim3(NT / BM, DM / BN), 256, 0, stream>>>(
            ysb, DI, out_w + (size_t)i * DM * DI, DI, h, DM,
            NT, DM, DI, nullptr, h, 0);
    }

    // 9. final rmsnorm
    rmsnorm_kernel<<<NT, 256, 0, stream>>>(h, normf_w, xn);
    // 10. head: logits = xn @ head_w^T + head_b  (2048 x 32000, K=768)
    sgemm_bt<<<dim3(NT / BM, (NVOCAB + BN - 1) / BN), 256, 0, stream>>>(
        xn, DM, head_w, DM, logits, NVOCAB,
        NT, NVOCAB, DM, head_b, nullptr, 0);
}

// Round 2
// 2547.501 us; speedup vs baseline: 1.6486x; 1.6486x over previous
//
#include <hip/hip_runtime.h>
#include <cmath>

// ---- problem constants ----
constexpr int DM     = 768;     // d_model
constexpr int DI     = 1536;    // d_inner
constexpr int DI2    = 3072;    // 2*d_inner
constexpr int DSTATE = 16;
constexpr int DTRANK = 48;
constexpr int NDBC   = 80;      // dt_rank + 2*d_state
constexpr int BB     = 2;
constexpr int LL     = 1024;
constexpr int NT     = BB * LL; // 2048 tokens
constexpr int NVOCAB = 32000;
constexpr float EPSF = 1e-5f;

typedef unsigned short ushort_t;
typedef __bf16 bf16x8 __attribute__((ext_vector_type(8)));
typedef float  f32x4  __attribute__((ext_vector_type(4)));

__device__ inline ushort_t f2bf(float x) {
    unsigned int u = __builtin_bit_cast(unsigned int, x);
    unsigned int r = (u + 0x7FFFu + ((u >> 16) & 1u)) >> 16;
    return (ushort_t)r;
}

// ------------------- fp32 -> bf16 bulk convert (RNE) -------------------
__global__ __launch_bounds__(256) void f2b_kernel(const float* __restrict__ in,
                                                  ushort_t* __restrict__ out, int n4) {
    int i = blockIdx.x * blockDim.x + threadIdx.x;
    if (i >= n4) return;
    float4 v = ((const float4*)in)[i];
    ushort4 o;
    o.x = f2bf(v.x); o.y = f2bf(v.y); o.z = f2bf(v.z); o.w = f2bf(v.w);
    ((ushort4*)out)[i] = o;
}

// ------------------- embedding gather -------------------
__global__ void embed_kernel(const int* __restrict__ x, const float* __restrict__ W,
                             float* __restrict__ h) {
    int t = blockIdx.x;
    int row = x[t];
    const float4* src = (const float4*)(W + (size_t)row * DM);
    float4* dst = (float4*)(h + (size_t)t * DM);
    for (int i = threadIdx.x; i < DM / 4; i += blockDim.x) dst[i] = src[i];
}

// ------------------- per-token RMSNorm, bf16 output -------------------
__global__ __launch_bounds__(256) void rmsnorm_kernel(const float* __restrict__ x,
                                                      const float* __restrict__ w,
                                                      ushort_t* __restrict__ o) {
    int t = blockIdx.x;
    const float* xr = x + (size_t)t * DM;
    float s = 0.f;
    for (int i = threadIdx.x; i < DM; i += 256) { float v = xr[i]; s += v * v; }
    #pragma unroll
    for (int off = 32; off >= 1; off >>= 1) s += __shfl_down(s, off, 64);
    __shared__ float wsum[4];
    if ((threadIdx.x & 63) == 0) wsum[threadIdx.x >> 6] = s;
    __syncthreads();
    float tot = wsum[0] + wsum[1] + wsum[2] + wsum[3];
    float r = rsqrtf(tot / DM + EPSF);
    ushort_t* orow = o + (size_t)t * DM;
    for (int i = threadIdx.x; i < DM; i += 256) orow[i] = f2bf(xr[i] * r * w[i]);
}

// ------------------- bf16 MFMA GEMM: C[m,n] = sum_k A[m,k]*W[n,k] -------------------
// m97-style: 128x128 tile, BK=32, 4 waves (2x2), 4x4 16x16x32 MFMA tiles per wave,
// global_load_lds width 16 staging, ds_read_b128 fragments.
// Requires M%128==0, N%128==0, K%32==0.
__device__ inline void gl_lds16(const void* g, void* l) {
    auto gp = (const __attribute__((address_space(1))) void*)(unsigned long long)(uintptr_t)g;
    auto lp = (__attribute__((address_space(3))) void*)(unsigned int)(uintptr_t)l;
    __builtin_amdgcn_global_load_lds(gp, lp, 16, 0, 0);
}

__global__ __launch_bounds__(256) void bgemm_bt(const ushort_t* __restrict__ A, int lda,
                                                const ushort_t* __restrict__ W, int ldw,
                                                float* __restrict__ C, int ldc,
                                                int K,
                                                const float* __restrict__ bias,
                                                const float* __restrict__ resid) {
    __shared__ ushort_t As[128 * 32];
    __shared__ ushort_t Bs[128 * 32];
    const int m0 = blockIdx.x * 128;
    const int n0 = blockIdx.y * 128;
    const int wave = threadIdx.x >> 6;
    const int lane = threadIdx.x & 63;
    const int lrow = lane >> 2;          // 0..15
    const int lcol = (lane & 3) * 8;     // bf16 elem offset (16B granules)

    f32x4 acc[4][4] = {};

    const ushort_t* Ab = A + (size_t)m0 * lda;
    const ushort_t* Wb = W + (size_t)n0 * ldw;
    const int wm = (wave >> 1) * 64;
    const int wn = (wave & 1) * 64;

    for (int k0 = 0; k0 < K; k0 += 32) {
        #pragma unroll
        for (int r = 0; r < 2; ++r) {
            const int rowbase = r * 64 + wave * 16;
            gl_lds16(Ab + (size_t)(rowbase + lrow) * lda + k0 + lcol,
                     (char*)As + rowbase * 64);
            gl_lds16(Wb + (size_t)(rowbase + lrow) * ldw + k0 + lcol,
                     (char*)Bs + rowbase * 64);
        }
        __syncthreads();

        bf16x8 af[4], bfr[4];
        #pragma unroll
        for (int i = 0; i < 4; ++i) {
            af[i]  = *(const bf16x8*)((char*)As + (wm + i * 16 + (lane & 15)) * 64 + (lane >> 4) * 16);
            bfr[i] = *(const bf16x8*)((char*)Bs + (wn + i * 16 + (lane & 15)) * 64 + (lane >> 4) * 16);
        }
        #pragma unroll
        for (int i = 0; i < 4; ++i)
            #pragma unroll
            for (int j = 0; j < 4; ++j)
                acc[i][j] = __builtin_amdgcn_mfma_f32_16x16x32_bf16(af[i], bfr[j], acc[i][j], 0, 0, 0);
        __syncthreads();
    }

    // epilogue: C/D layout col=lane&15, row=(lane>>4)*4+reg
    const int cn = lane & 15;
    const int cr = (lane >> 4) * 4;
    #pragma unroll
    for (int i = 0; i < 4; ++i) {
        #pragma unroll
        for (int j = 0; j < 4; ++j) {
            const int col = n0 + wn + j * 16 + cn;
            const float bv = bias ? bias[col] : 0.f;
            #pragma unroll
            for (int rr = 0; rr < 4; ++rr) {
                const int row = m0 + wm + i * 16 + cr + rr;
                const size_t idx = (size_t)row * ldc + col;
                float v = acc[i][j][rr] + bv;
                if (resid) v += resid[idx];
                C[idx] = v;
            }
        }
    }
}

// ------------------- fp32 tiled GEMM (small N / small K cases) -------------------
constexpr int BM = 64, BN = 64, BK = 16;
__global__ __launch_bounds__(256) void sgemm_bt(const float* __restrict__ A, int lda,
                                                const float* __restrict__ W, int ldw,
                                                float* __restrict__ C, int ldc,
                                                int M, int N, int K,
                                                const float* __restrict__ bias,
                                                const float* __restrict__ resid,
                                                int act) {
    __shared__ float As[BK][BM];
    __shared__ float Ws[BK][BN];
    const int m0 = blockIdx.x * BM;
    const int n0 = blockIdx.y * BN;
    const int tid = threadIdx.x;
    const int tn = tid & 15, tm = tid >> 4;
    const int lr = tid >> 2;
    const int lk = (tid & 3) * 4;

    float acc[4][4] = {};

    for (int k0 = 0; k0 < K; k0 += BK) {
        {
            float4 v = *(const float4*)(A + (size_t)(m0 + lr) * lda + k0 + lk);
            As[lk + 0][lr] = v.x; As[lk + 1][lr] = v.y;
            As[lk + 2][lr] = v.z; As[lk + 3][lr] = v.w;
            int n = n0 + lr;
            float4 u = make_float4(0.f, 0.f, 0.f, 0.f);
            if (n < N) u = *(const float4*)(W + (size_t)n * ldw + k0 + lk);
            Ws[lk + 0][lr] = u.x; Ws[lk + 1][lr] = u.y;
            Ws[lk + 2][lr] = u.z; Ws[lk + 3][lr] = u.w;
        }
        __syncthreads();
        #pragma unroll
        for (int kk = 0; kk < BK; ++kk) {
            float4 a = *(const float4*)&As[kk][tm * 4];
            float4 w = *(const float4*)&Ws[kk][tn * 4];
            acc[0][0] += a.x * w.x; acc[0][1] += a.x * w.y; acc[0][2] += a.x * w.z; acc[0][3] += a.x * w.w;
            acc[1][0] += a.y * w.x; acc[1][1] += a.y * w.y; acc[1][2] += a.y * w.z; acc[1][3] += a.y * w.w;
            acc[2][0] += a.z * w.x; acc[2][1] += a.z * w.y; acc[2][2] += a.z * w.z; acc[2][3] += a.z * w.w;
            acc[3][0] += a.w * w.x; acc[3][1] += a.w * w.y; acc[3][2] += a.w * w.z; acc[3][3] += a.w * w.w;
        }
        __syncthreads();
    }

    #pragma unroll
    for (int i = 0; i < 4; ++i) {
        int m = m0 + tm * 4 + i;
        #pragma unroll
        for (int j = 0; j < 4; ++j) {
            int n = n0 + tn * 4 + j;
            if (n < N) {
                float v = acc[i][j];
                if (bias)  v += bias[n];
                if (resid) v += resid[(size_t)m * ldc + n];
                if (act == 1) v = (v > 20.f) ? v : log1pf(expf(v));
                C[(size_t)m * ldc + n] = v;
            }
        }
    }
}

// ------------------- causal depthwise conv (k=4) + bias + silu -------------------
__global__ void conv_silu_kernel(const float* __restrict__ xz, const float* __restrict__ cw,
                                 const float* __restrict__ cb, float* __restrict__ xa) {
    int idx = blockIdx.x * blockDim.x + threadIdx.x;
    if (idx >= NT * DI) return;
    int e = idx % DI;
    int t = idx / DI;
    int l = t & (LL - 1);
    float acc = cb[e];
    #pragma unroll
    for (int k = 0; k < 4; ++k) {
        int ll = l - 3 + k;
        if (ll >= 0) acc += cw[e * 4 + k] * xz[(size_t)(t - 3 + k) * DI2 + e];
    }
    xa[idx] = acc / (1.f + expf(-acc));   // silu
}

// ------------------- fused selective scan (bf16 output) -------------------
__global__ __launch_bounds__(256) void scan_kernel(const float* __restrict__ delta,  // NT x DI
                                                   const float* __restrict__ xa,     // NT x DI
                                                   const float* __restrict__ dbc,    // NT x 80
                                                   const float* __restrict__ xz,     // NT x 3072 (z at +DI)
                                                   const float* __restrict__ A_log,  // DI x 16
                                                   const float* __restrict__ Dp,     // DI
                                                   ushort_t* __restrict__ ys) {      // NT x DI (bf16)
    const int n = threadIdx.x & 15;
    const int e = blockIdx.x * 16 + (threadIdx.x >> 4);
    const int b = blockIdx.y;
    const float Aen = -expf(A_log[e * 16 + n]);
    const float dpe = Dp[e];
    float h = 0.f;
    const int base = b * LL;
    for (int l = 0; l < LL; ++l) {
        const int t = base + l;
        float d  = delta[(size_t)t * DI + e];
        float xv = xa[(size_t)t * DI + e];
        float bm = dbc[(size_t)t * NDBC + DTRANK + n];
        float cm = dbc[(size_t)t * NDBC + DTRANK + DSTATE + n];
        float dA = expf(d * Aen);
        h = dA * h + d * bm * xv;
        float y = h * cm;
        y += __shfl_xor(y, 8, 64);
        y += __shfl_xor(y, 4, 64);
        y += __shfl_xor(y, 2, 64);
        y += __shfl_xor(y, 1, 64);
        if (n == 0) {
            float z = xz[(size_t)t * DI2 + DI + e];
            float sz = z / (1.f + expf(-z));
            ys[(size_t)t * DI + e] = f2bf((y + dpe * xv) * sz);
        }
    }
}

// ------------------- host launcher -------------------
extern "C" void kernel_launch(void* const* d_in, const int* in_sizes, int n_in,
                              void* d_out, int out_size, void* d_ws, size_t ws_size,
                              hipStream_t stream) {
    const int*   x        = (const int*)  d_in[0];
    const float* embed_W  = (const float*)d_in[1];
    const float* norm_w   = (const float*)d_in[2];
    const float* in_w     = (const float*)d_in[3];   // (2, 3072, 768)
    const float* conv_w   = (const float*)d_in[4];
    const float* conv_b   = (const float*)d_in[5];
    const float* xproj_w  = (const float*)d_in[6];   // (2, 80, 1536)
    const float* dt_w     = (const float*)d_in[7];   // (2, 1536, 48)
    const float* dt_b     = (const float*)d_in[8];
    const float* A_log    = (const float*)d_in[9];
    const float* D_param  = (const float*)d_in[10];
    const float* out_w    = (const float*)d_in[11];  // (2, 768, 1536)
    const float* normf_w  = (const float*)d_in[12];
    const float* head_w   = (const float*)d_in[13];  // (32000, 768)
    const float* head_b   = (const float*)d_in[14];
    float* logits = (float*)d_out;

    // ---- workspace carve-up ----
    float* ws    = (float*)d_ws;
    float* h     = ws;                         // NT*DM
    float* xz    = h     + (size_t)NT * DM;    // NT*DI2
    float* xa    = xz    + (size_t)NT * DI2;   // NT*DI
    float* dbc   = xa    + (size_t)NT * DI;    // NT*NDBC
    float* delta = dbc   + (size_t)NT * NDBC;  // NT*DI
    ushort_t* in_wb  = (ushort_t*)(delta + (size_t)NT * DI);  // 2*DI2*DM
    ushort_t* out_wb = in_wb  + (size_t)2 * DI2 * DM;         // 2*DM*DI
    ushort_t* xnb    = out_wb + (size_t)2 * DM * DI;          // NT*DM
    ushort_t* ys16   = xnb    + (size_t)NT * DM;              // NT*DI
    // head_wb (32000*768 bf16 = 49.2 MB) aliases xz..delta (50.9 MB), dead at head time
    ushort_t* head_wb = (ushort_t*)xz;

    // 1. embedding
    embed_kernel<<<NT, 192, 0, stream>>>(x, embed_W, h);

    // 2. weight conversions (layer weights; head_w later, its buffer aliases xz)
    {
        int n4 = 2 * DI2 * DM / 4;
        f2b_kernel<<<(n4 + 255) / 256, 256, 0, stream>>>(in_w, in_wb, n4);
        n4 = 2 * DM * DI / 4;
        f2b_kernel<<<(n4 + 255) / 256, 256, 0, stream>>>(out_w, out_wb, n4);
    }

    for (int i = 0; i < 2; ++i) {
        // rmsnorm -> bf16
        rmsnorm_kernel<<<NT, 256, 0, stream>>>(h, norm_w + (size_t)i * DM, xnb);
        // in_proj: xz = xn @ in_w^T   (2048 x 3072, K=768) [MFMA]
        bgemm_bt<<<dim3(NT / 128, DI2 / 128), 256, 0, stream>>>(
            xnb, DM, in_wb + (size_t)i * DI2 * DM, DM, xz, DI2, DM, nullptr, nullptr);
        // conv + silu
        conv_silu_kernel<<<(NT * DI + 255) / 256, 256, 0, stream>>>(
            xz, conv_w + (size_t)i * DI * 4, conv_b + (size_t)i * DI, xa);
        // x_proj: dbc = xa @ xproj_w^T  (2048 x 80, K=1536) [fp32]
        sgemm_bt<<<dim3(NT / BM, (NDBC + BN - 1) / BN), 256, 0, stream>>>(
            xa, DI, xproj_w + (size_t)i * NDBC * DI, DI, dbc, NDBC,
            NT, NDBC, DI, nullptr, nullptr, 0);
        // dt_proj + bias + softplus  (2048 x 1536, K=48) [fp32]
        sgemm_bt<<<dim3(NT / BM, DI / BN), 256, 0, stream>>>(
            dbc, NDBC, dt_w + (size_t)i * DI * DTRANK, DTRANK, delta, DI,
            NT, DI, DTRANK, dt_b + (size_t)i * DI, nullptr, 1);
        // fused selective scan -> ys (bf16)
        scan_kernel<<<dim3(DI / 16, BB), 256, 0, stream>>>(
            delta, xa, dbc, xz, A_log + (size_t)i * DI * DSTATE,
            D_param + (size_t)i * DI, ys16);
        // out_proj + residual: h += ys @ out_w^T  (2048 x 768, K=1536) [MFMA]
        bgemm_bt<<<dim3(NT / 128, DM / 128), 256, 0, stream>>>(
            ys16, DI, out_wb + (size_t)i * DM * DI, DI, h, DM, DI, nullptr, h);
    }

    // final rmsnorm -> bf16
    rmsnorm_kernel<<<NT, 256, 0, stream>>>(h, normf_w, xnb);
    // head weight conversion (xz region now dead)
    {
        int n4 = NVOCAB * DM / 4;
        f2b_kernel<<<(n4 + 255) / 256, 256, 0, stream>>>(head_w, head_wb, n4);
    }
    // head: logits = xn @ head_w^T + head_b  (2048 x 32000, K=768) [MFMA]
    bgemm_bt<<<dim3(NT / 128, NVOCAB / 128), 256, 0, stream>>>(
        xnb, DM, head_wb, DM, logits, NVOCAB, DM, head_b, nullptr);
}